// Round 1
// baseline (1452.674 us; speedup 1.0000x reference)
//
#include <hip/hip_runtime.h>

#define N_NODES 86016
#define N_EDGES 4194304
#define HID 32
#define B_GR 1024
#define NPG 84
#define NEG 0.2f

// ---- workspace layout (bytes) ----
constexpr size_t O_SRC  = 0;                                   // E ints   (src sorted by dst)
constexpr size_t O_EA   = O_SRC + (size_t)N_EDGES * 4;         // E float2 (edge attr sorted by dst)
constexpr size_t O_HT   = O_EA  + (size_t)N_EDGES * 8;         // N*32 f32 (transformed feats)
constexpr size_t O_HB   = O_HT  + (size_t)N_NODES * HID * 4;   // N*32 f32 (aggregated feats)
constexpr size_t O_AS   = O_HB  + (size_t)N_NODES * HID * 4;   // N f32  alpha_src per node
constexpr size_t O_AD   = O_AS  + (size_t)N_NODES * 4;         // N f32  alpha_dst per node
constexpr size_t O_DEG  = O_AD  + (size_t)N_NODES * 4;         // N int
constexpr size_t O_FILL = O_DEG + (size_t)N_NODES * 4;         // N int
constexpr size_t O_ROW  = O_FILL + (size_t)N_NODES * 4;        // N+1 int
constexpr size_t O_BSUM = O_ROW + (size_t)(N_NODES + 1) * 4 + 12; // 84 int (16B aligned)
constexpr size_t O_BOFF = O_BSUM + 84 * 4;                     // 84 int
constexpr size_t O_FOLD = O_BOFF + 84 * 4;                     // 8 f32 (We@att_edge per layer)

__global__ void k_zero(int* __restrict__ p, int n) {
    int i = blockIdx.x * blockDim.x + threadIdx.x;
    if (i < n) p[i] = 0;
}

__global__ void k_count(const int* __restrict__ dst, int* __restrict__ deg) {
    int stride = gridDim.x * blockDim.x;
    for (int e = blockIdx.x * blockDim.x + threadIdx.x; e < N_EDGES; e += stride)
        atomicAdd(&deg[dst[e]], 1);
}

// per-block inclusive scan of 1024 deg values -> row[gi+1] (local), block total -> bsum
__global__ void k_scanA(const int* __restrict__ deg, int* __restrict__ row, int* __restrict__ bsum) {
    __shared__ int s[1024];
    int t = threadIdx.x;
    int gi = blockIdx.x * 1024 + t;
    s[t] = deg[gi];
    __syncthreads();
    for (int off = 1; off < 1024; off <<= 1) {
        int x = (t >= off) ? s[t - off] : 0;
        __syncthreads();
        s[t] += x;
        __syncthreads();
    }
    row[gi + 1] = s[t];
    if (t == 1023) bsum[blockIdx.x] = s[t];
}

__global__ void k_scanB(const int* __restrict__ bsum, int* __restrict__ boff) {
    __shared__ int s[84];
    int t = threadIdx.x;
    if (t < 84) s[t] = bsum[t];
    __syncthreads();
    if (t == 0) {
        int r = 0;
        for (int b = 0; b < 84; ++b) { int v = s[b]; s[b] = r; r += v; }
    }
    __syncthreads();
    if (t < 84) boff[t] = s[t];
}

__global__ void k_scanC(int* __restrict__ row, const int* __restrict__ boff) {
    int t = threadIdx.x;
    int gi = blockIdx.x * 1024 + t;
    row[gi + 1] += boff[blockIdx.x];
    if (gi == 0) row[0] = 0;
}

__global__ void k_scatter(const int* __restrict__ ei, const float2* __restrict__ ea,
                          const int* __restrict__ row, int* __restrict__ fill,
                          int* __restrict__ ssorted, float2* __restrict__ easorted) {
    int stride = gridDim.x * blockDim.x;
    for (int e = blockIdx.x * blockDim.x + threadIdx.x; e < N_EDGES; e += stride) {
        int s = ei[e];
        int d = ei[N_EDGES + e];
        int pos = row[d] + atomicAdd(&fill[d], 1);
        ssorted[pos] = s;
        easorted[pos] = ea[e];
    }
}

// fold[l*2+c] = sum_j We[l][c][j] * att_edge[l][j]
__global__ void k_fold(const float* __restrict__ We, const float* __restrict__ ae,
                       float* __restrict__ fold) {
    int t = threadIdx.x;
    if (t < 8) {
        int l = t >> 1, c = t & 1;
        float s = 0.f;
        for (int j = 0; j < 32; ++j) s += We[l * 64 + c * 32 + j] * ae[l * 32 + j];
        fold[t] = s;
    }
}

// layer-0 transform: h = x * W0 (outer product), plus per-node alpha_src/alpha_dst
__global__ void k_transform0(const float* __restrict__ x, const float* __restrict__ W0,
                             const float* __restrict__ as_w, const float* __restrict__ ad_w,
                             float* __restrict__ hout, float* __restrict__ as_arr,
                             float* __restrict__ ad_arr) {
    int tid = blockIdx.x * 256 + threadIdx.x;
    int j = tid & 31;
    int n = tid >> 5;
    float acc = x[n] * W0[j];
    hout[tid] = acc;
    float v1 = acc * as_w[j], v2 = acc * ad_w[j];
#pragma unroll
    for (int m = 16; m >= 1; m >>= 1) {
        v1 += __shfl_xor(v1, m);
        v2 += __shfl_xor(v2, m);
    }
    if (j == 0) { as_arr[n] = v1; ad_arr[n] = v2; }
}

// generic transform: h2[n][j] = sum_k h[n][k] * W[k][j], plus alpha_src/alpha_dst
__global__ void k_transform(const float* __restrict__ hin, const float* __restrict__ W,
                            const float* __restrict__ as_w, const float* __restrict__ ad_w,
                            float* __restrict__ hout, float* __restrict__ as_arr,
                            float* __restrict__ ad_arr) {
    __shared__ float Wl[1024];
    int t = threadIdx.x;
#pragma unroll
    for (int i = 0; i < 4; ++i) Wl[t + i * 256] = W[t + i * 256];
    __syncthreads();
    int tid = blockIdx.x * 256 + t;
    int j = tid & 31;
    int n = tid >> 5;
    float hv = hin[tid];
    float acc = 0.f;
#pragma unroll
    for (int k = 0; k < 32; ++k) acc += __shfl(hv, k, 32) * Wl[k * 32 + j];
    hout[tid] = acc;
    float v1 = acc * as_w[j], v2 = acc * ad_w[j];
#pragma unroll
    for (int m = 16; m >= 1; m >>= 1) {
        v1 += __shfl_xor(v1, m);
        v2 += __shfl_xor(v2, m);
    }
    if (j == 0) { as_arr[n] = v1; ad_arr[n] = v2; }
}

// one wave per node; lanes&31 = feature dim; two edges per iteration (one per half-wave).
// Softmax without max-subtraction (logits bounded ~O(1)); self-loop's mean edge attr
// folded in via easum (linearity of the 2-dot).
__global__ void k_gather(const float* __restrict__ hT, const int* __restrict__ ssorted,
                         const float2* __restrict__ easorted, const int* __restrict__ row,
                         const float* __restrict__ as_arr, const float* __restrict__ ad_arr,
                         const float* __restrict__ fold, const float* __restrict__ bias,
                         float* __restrict__ out, int do_relu) {
    int lane = threadIdx.x & 63;
    int n = blockIdx.x * 4 + (threadIdx.x >> 6);
    int j = lane & 31;
    int half = lane >> 5;
    int beg = row[n], end = row[n + 1];
    float c_dst = ad_arr[n];
    float f0 = fold[0], f1 = fold[1];
    float acc = 0.f, den = 0.f, esum = 0.f;
    for (int e = beg + half; e < end; e += 2) {
        int s = ssorted[e];
        float2 ea = easorted[e];
        float edot = ea.x * f0 + ea.y * f1;
        float lg = as_arr[s] + c_dst + edot;
        lg = fmaxf(lg, NEG * lg);          // leaky_relu(0.2)
        float w = __expf(lg);
        den += w;
        esum += edot;
        acc += w * hT[(s << 5) + j];
    }
    acc += __shfl_xor(acc, 32);
    den += __shfl_xor(den, 32);
    esum += __shfl_xor(esum, 32);
    // self loop: edge attr = mean of incoming (0 if deg==0), src = n
    int dg = end - beg;
    float el = esum / fmaxf((float)dg, 1.0f);
    float lg = as_arr[n] + c_dst + el;
    lg = fmaxf(lg, NEG * lg);
    float w = __expf(lg);
    den += w;
    acc += w * hT[(n << 5) + j];
    float o = acc / den + bias[j];
    if (do_relu) o = fmaxf(o, 0.f);
    if (half == 0) out[(n << 5) + j] = o;
}

// global_add_pool over 84-node graphs, then linear(32->1) + relu
__global__ void k_pool(const float* __restrict__ h, const float* __restrict__ lw,
                       const float* __restrict__ lb, float* __restrict__ out) {
    int lane = threadIdx.x & 63;
    int g = blockIdx.x * 4 + (threadIdx.x >> 6);
    int j = lane & 31;
    int half = lane >> 5;
    const float* base = h + (size_t)g * NPG * HID;
    float acc = 0.f;
    for (int i = half; i < NPG; i += 2) acc += base[i * HID + j];
    acc += __shfl_xor(acc, 32);
    float v = acc * lw[j];
#pragma unroll
    for (int m = 16; m >= 1; m >>= 1) v += __shfl_xor(v, m);
    if (lane == 0) out[g] = fmaxf(v + lb[0], 0.f);
}

extern "C" void kernel_launch(void* const* d_in, const int* in_sizes, int n_in,
                              void* d_out, int out_size, void* d_ws, size_t ws_size,
                              hipStream_t stream) {
    const float* x        = (const float*)d_in[0];
    const int*   ei       = (const int*)d_in[1];
    const float* eattr    = (const float*)d_in[2];
    const float* W0       = (const float*)d_in[3];
    const float* Ws       = (const float*)d_in[4];
    const float* att_src  = (const float*)d_in[5];
    const float* att_dst  = (const float*)d_in[6];
    const float* We       = (const float*)d_in[7];
    const float* att_edge = (const float*)d_in[8];
    const float* bias     = (const float*)d_in[9];
    const float* lin_w    = (const float*)d_in[10];
    const float* lin_b    = (const float*)d_in[11];
    float* out = (float*)d_out;

    char* w = (char*)d_ws;
    int*    ssorted  = (int*)(w + O_SRC);
    float2* easorted = (float2*)(w + O_EA);
    float*  hT       = (float*)(w + O_HT);
    float*  hB       = (float*)(w + O_HB);
    float*  as_arr   = (float*)(w + O_AS);
    float*  ad_arr   = (float*)(w + O_AD);
    int*    deg      = (int*)(w + O_DEG);
    int*    row      = (int*)(w + O_ROW);
    int*    fill     = (int*)(w + O_FILL);
    int*    bsum     = (int*)(w + O_BSUM);
    int*    boff     = (int*)(w + O_BOFF);
    float*  fold     = (float*)(w + O_FOLD);

    // ---- build CSR by dst (deg + fill are contiguous: zero both) ----
    k_zero<<<(2 * N_NODES + 255) / 256, 256, 0, stream>>>(deg, 2 * N_NODES);
    k_count<<<4096, 256, 0, stream>>>(ei + N_EDGES, deg);
    k_scanA<<<84, 1024, 0, stream>>>(deg, row, bsum);
    k_scanB<<<1, 128, 0, stream>>>(bsum, boff);
    k_scanC<<<84, 1024, 0, stream>>>(row, boff);
    k_scatter<<<8192, 256, 0, stream>>>(ei, (const float2*)eattr, row, fill, ssorted, easorted);
    k_fold<<<1, 64, 0, stream>>>(We, att_edge, fold);

    // ---- layer 0 ----
    k_transform0<<<N_NODES * HID / 256, 256, 0, stream>>>(x, W0, att_src, att_dst,
                                                          hT, as_arr, ad_arr);
    k_gather<<<N_NODES / 4, 256, 0, stream>>>(hT, ssorted, easorted, row, as_arr, ad_arr,
                                              fold, bias, hB, 1);
    // ---- layers 1..3 ----
    for (int l = 1; l < 4; ++l) {
        k_transform<<<N_NODES * HID / 256, 256, 0, stream>>>(
            hB, Ws + (size_t)(l - 1) * HID * HID, att_src + l * HID, att_dst + l * HID,
            hT, as_arr, ad_arr);
        k_gather<<<N_NODES / 4, 256, 0, stream>>>(hT, ssorted, easorted, row, as_arr, ad_arr,
                                                  fold + 2 * l, bias + l * HID, hB,
                                                  (l < 3) ? 1 : 0);
    }

    // ---- pool + linear + relu ----
    k_pool<<<B_GR / 4, 256, 0, stream>>>(hB, lin_w, lin_b, out);
}

// Round 2
// 1107.559 us; speedup vs baseline: 1.3116x; 1.3116x over previous
//
#include <hip/hip_runtime.h>

#define N_NODES 86016
#define N_EDGES 4194304
#define HID 32
#define B_GR 1024
#define NPG 84
#define NEG 0.2f

// ---- workspace layout (bytes) ----
// Edge record: float4 {src (bit-cast int), ea.x, ea.y, unused} — ONE 16B aligned
// write per edge during scatter (one cache-line touch instead of two).
constexpr size_t O_REC  = 0;                                   // E * 16 B
constexpr size_t O_HT   = O_REC + (size_t)N_EDGES * 16;        // N*32 f32 (transformed feats)
constexpr size_t O_HB   = O_HT  + (size_t)N_NODES * HID * 4;   // N*32 f32 (aggregated feats)
constexpr size_t O_AS   = O_HB  + (size_t)N_NODES * HID * 4;   // N f32  alpha_src per node
constexpr size_t O_AD   = O_AS  + (size_t)N_NODES * 4;         // N f32  alpha_dst per node
constexpr size_t O_DEG  = O_AD  + (size_t)N_NODES * 4;         // N int
constexpr size_t O_FILL = O_DEG + (size_t)N_NODES * 4;         // N int
constexpr size_t O_ROW  = O_FILL + (size_t)N_NODES * 4;        // N+1 int
constexpr size_t O_BSUM = O_ROW + (size_t)(N_NODES + 1) * 4 + 12; // 84 int (16B aligned)
constexpr size_t O_BOFF = O_BSUM + 84 * 4;                     // 84 int
constexpr size_t O_FOLD = O_BOFF + 84 * 4;                     // 8 f32 (We@att_edge per layer)

__global__ void k_zero(int* __restrict__ p, int n) {
    int i = blockIdx.x * blockDim.x + threadIdx.x;
    if (i < n) p[i] = 0;
}

__global__ void k_count(const int* __restrict__ dst, int* __restrict__ deg) {
    int stride = gridDim.x * blockDim.x;
    for (int e = blockIdx.x * blockDim.x + threadIdx.x; e < N_EDGES; e += stride)
        atomicAdd(&deg[dst[e]], 1);
}

// per-block inclusive scan of 1024 deg values -> row[gi+1] (local), block total -> bsum
__global__ void k_scanA(const int* __restrict__ deg, int* __restrict__ row, int* __restrict__ bsum) {
    __shared__ int s[1024];
    int t = threadIdx.x;
    int gi = blockIdx.x * 1024 + t;
    s[t] = deg[gi];
    __syncthreads();
    for (int off = 1; off < 1024; off <<= 1) {
        int x = (t >= off) ? s[t - off] : 0;
        __syncthreads();
        s[t] += x;
        __syncthreads();
    }
    row[gi + 1] = s[t];
    if (t == 1023) bsum[blockIdx.x] = s[t];
}

__global__ void k_scanB(const int* __restrict__ bsum, int* __restrict__ boff) {
    __shared__ int s[84];
    int t = threadIdx.x;
    if (t < 84) s[t] = bsum[t];
    __syncthreads();
    if (t == 0) {
        int r = 0;
        for (int b = 0; b < 84; ++b) { int v = s[b]; s[b] = r; r += v; }
    }
    __syncthreads();
    if (t < 84) boff[t] = s[t];
}

__global__ void k_scanC(int* __restrict__ row, const int* __restrict__ boff) {
    int t = threadIdx.x;
    int gi = blockIdx.x * 1024 + t;
    row[gi + 1] += boff[blockIdx.x];
    if (gi == 0) row[0] = 0;
}

__global__ void k_scatter(const int* __restrict__ ei, const float2* __restrict__ ea,
                          const int* __restrict__ row, int* __restrict__ fill,
                          float4* __restrict__ rec) {
    int stride = gridDim.x * blockDim.x;
    for (int e = blockIdx.x * blockDim.x + threadIdx.x; e < N_EDGES; e += stride) {
        int s = ei[e];
        int d = ei[N_EDGES + e];
        float2 a = ea[e];
        int pos = row[d] + atomicAdd(&fill[d], 1);
        float4 r;
        r.x = __int_as_float(s);
        r.y = a.x;
        r.z = a.y;
        r.w = 0.f;
        rec[pos] = r;   // single 16B write -> single line touch per edge
    }
}

// fold[l*2+c] = sum_j We[l][c][j] * att_edge[l][j]
__global__ void k_fold(const float* __restrict__ We, const float* __restrict__ ae,
                       float* __restrict__ fold) {
    int t = threadIdx.x;
    if (t < 8) {
        int l = t >> 1, c = t & 1;
        float s = 0.f;
        for (int j = 0; j < 32; ++j) s += We[l * 64 + c * 32 + j] * ae[l * 32 + j];
        fold[t] = s;
    }
}

// layer-0 transform: h = x * W0 (outer product), plus per-node alpha_src/alpha_dst
__global__ void k_transform0(const float* __restrict__ x, const float* __restrict__ W0,
                             const float* __restrict__ as_w, const float* __restrict__ ad_w,
                             float* __restrict__ hout, float* __restrict__ as_arr,
                             float* __restrict__ ad_arr) {
    int tid = blockIdx.x * 256 + threadIdx.x;
    int j = tid & 31;
    int n = tid >> 5;
    float acc = x[n] * W0[j];
    hout[tid] = acc;
    float v1 = acc * as_w[j], v2 = acc * ad_w[j];
#pragma unroll
    for (int m = 16; m >= 1; m >>= 1) {
        v1 += __shfl_xor(v1, m);
        v2 += __shfl_xor(v2, m);
    }
    if (j == 0) { as_arr[n] = v1; ad_arr[n] = v2; }
}

// generic transform: h2[n][j] = sum_k h[n][k] * W[k][j], plus alpha_src/alpha_dst
__global__ void k_transform(const float* __restrict__ hin, const float* __restrict__ W,
                            const float* __restrict__ as_w, const float* __restrict__ ad_w,
                            float* __restrict__ hout, float* __restrict__ as_arr,
                            float* __restrict__ ad_arr) {
    __shared__ float Wl[1024];
    int t = threadIdx.x;
#pragma unroll
    for (int i = 0; i < 4; ++i) Wl[t + i * 256] = W[t + i * 256];
    __syncthreads();
    int tid = blockIdx.x * 256 + t;
    int j = tid & 31;
    int n = tid >> 5;
    float hv = hin[tid];
    float acc = 0.f;
#pragma unroll
    for (int k = 0; k < 32; ++k) acc += __shfl(hv, k, 32) * Wl[k * 32 + j];
    hout[tid] = acc;
    float v1 = acc * as_w[j], v2 = acc * ad_w[j];
#pragma unroll
    for (int m = 16; m >= 1; m >>= 1) {
        v1 += __shfl_xor(v1, m);
        v2 += __shfl_xor(v2, m);
    }
    if (j == 0) { as_arr[n] = v1; ad_arr[n] = v2; }
}

// one wave per node; lane&31 = feature dim; halves of the wave take alternating
// edges; 2x unrolled (4 edges in flight per wave iteration) for MLP.
// Softmax without max-subtraction (logits bounded ~O(1)); self-loop's mean edge
// attr folded in via esum (linearity of the 2-dot).
__global__ void k_gather(const float* __restrict__ hT, const float4* __restrict__ rec,
                         const int* __restrict__ row,
                         const float* __restrict__ as_arr, const float* __restrict__ ad_arr,
                         const float* __restrict__ fold, const float* __restrict__ bias,
                         float* __restrict__ out, int do_relu) {
    int lane = threadIdx.x & 63;
    int n = blockIdx.x * 4 + (threadIdx.x >> 6);
    int j = lane & 31;
    int half = lane >> 5;
    int beg = row[n], end = row[n + 1];
    float c_dst = ad_arr[n];
    float f0 = fold[0], f1 = fold[1];
    float acc = 0.f, den = 0.f, esum = 0.f;
    int e = beg + half;
    for (; e + 2 < end; e += 4) {
        float4 r0 = rec[e];
        float4 r1 = rec[e + 2];
        int s0 = __float_as_int(r0.x);
        int s1 = __float_as_int(r1.x);
        float h0 = hT[(s0 << 5) + j];
        float h1 = hT[(s1 << 5) + j];
        float a0 = as_arr[s0];
        float a1 = as_arr[s1];
        float ed0 = r0.y * f0 + r0.z * f1;
        float ed1 = r1.y * f0 + r1.z * f1;
        float lg0 = a0 + c_dst + ed0; lg0 = fmaxf(lg0, NEG * lg0);
        float lg1 = a1 + c_dst + ed1; lg1 = fmaxf(lg1, NEG * lg1);
        float w0 = __expf(lg0);
        float w1 = __expf(lg1);
        den += w0 + w1;
        esum += ed0 + ed1;
        acc += w0 * h0;
        acc += w1 * h1;
    }
    for (; e < end; e += 2) {
        float4 r = rec[e];
        int s = __float_as_int(r.x);
        float h = hT[(s << 5) + j];
        float ed = r.y * f0 + r.z * f1;
        float lg = as_arr[s] + c_dst + ed;
        lg = fmaxf(lg, NEG * lg);
        float w = __expf(lg);
        den += w;
        esum += ed;
        acc += w * h;
    }
    acc += __shfl_xor(acc, 32);
    den += __shfl_xor(den, 32);
    esum += __shfl_xor(esum, 32);
    // self loop: edge attr = mean of incoming (0 if deg==0), src = n
    int dg = end - beg;
    float el = esum / fmaxf((float)dg, 1.0f);
    float lg = as_arr[n] + c_dst + el;
    lg = fmaxf(lg, NEG * lg);
    float w = __expf(lg);
    den += w;
    acc += w * hT[(n << 5) + j];
    float o = acc / den + bias[j];
    if (do_relu) o = fmaxf(o, 0.f);
    if (half == 0) out[(n << 5) + j] = o;
}

// global_add_pool over 84-node graphs, then linear(32->1) + relu
__global__ void k_pool(const float* __restrict__ h, const float* __restrict__ lw,
                       const float* __restrict__ lb, float* __restrict__ out) {
    int lane = threadIdx.x & 63;
    int g = blockIdx.x * 4 + (threadIdx.x >> 6);
    int j = lane & 31;
    int half = lane >> 5;
    const float* base = h + (size_t)g * NPG * HID;
    float acc = 0.f;
    for (int i = half; i < NPG; i += 2) acc += base[i * HID + j];
    acc += __shfl_xor(acc, 32);
    float v = acc * lw[j];
#pragma unroll
    for (int m = 16; m >= 1; m >>= 1) v += __shfl_xor(v, m);
    if (lane == 0) out[g] = fmaxf(v + lb[0], 0.f);
}

extern "C" void kernel_launch(void* const* d_in, const int* in_sizes, int n_in,
                              void* d_out, int out_size, void* d_ws, size_t ws_size,
                              hipStream_t stream) {
    const float* x        = (const float*)d_in[0];
    const int*   ei       = (const int*)d_in[1];
    const float* eattr    = (const float*)d_in[2];
    const float* W0       = (const float*)d_in[3];
    const float* Ws       = (const float*)d_in[4];
    const float* att_src  = (const float*)d_in[5];
    const float* att_dst  = (const float*)d_in[6];
    const float* We       = (const float*)d_in[7];
    const float* att_edge = (const float*)d_in[8];
    const float* bias     = (const float*)d_in[9];
    const float* lin_w    = (const float*)d_in[10];
    const float* lin_b    = (const float*)d_in[11];
    float* out = (float*)d_out;

    char* w = (char*)d_ws;
    float4* rec      = (float4*)(w + O_REC);
    float*  hT       = (float*)(w + O_HT);
    float*  hB       = (float*)(w + O_HB);
    float*  as_arr   = (float*)(w + O_AS);
    float*  ad_arr   = (float*)(w + O_AD);
    int*    deg      = (int*)(w + O_DEG);
    int*    row      = (int*)(w + O_ROW);
    int*    fill     = (int*)(w + O_FILL);
    int*    bsum     = (int*)(w + O_BSUM);
    int*    boff     = (int*)(w + O_BOFF);
    float*  fold     = (float*)(w + O_FOLD);

    // ---- build CSR by dst (deg + fill are contiguous: zero both) ----
    k_zero<<<(2 * N_NODES + 255) / 256, 256, 0, stream>>>(deg, 2 * N_NODES);
    k_count<<<4096, 256, 0, stream>>>(ei + N_EDGES, deg);
    k_scanA<<<84, 1024, 0, stream>>>(deg, row, bsum);
    k_scanB<<<1, 128, 0, stream>>>(bsum, boff);
    k_scanC<<<84, 1024, 0, stream>>>(row, boff);
    k_scatter<<<8192, 256, 0, stream>>>(ei, (const float2*)eattr, row, fill, rec);
    k_fold<<<1, 64, 0, stream>>>(We, att_edge, fold);

    // ---- layer 0 ----
    k_transform0<<<N_NODES * HID / 256, 256, 0, stream>>>(x, W0, att_src, att_dst,
                                                          hT, as_arr, ad_arr);
    k_gather<<<N_NODES / 4, 256, 0, stream>>>(hT, rec, row, as_arr, ad_arr,
                                              fold, bias, hB, 1);
    // ---- layers 1..3 ----
    for (int l = 1; l < 4; ++l) {
        k_transform<<<N_NODES * HID / 256, 256, 0, stream>>>(
            hB, Ws + (size_t)(l - 1) * HID * HID, att_src + l * HID, att_dst + l * HID,
            hT, as_arr, ad_arr);
        k_gather<<<N_NODES / 4, 256, 0, stream>>>(hT, rec, row, as_arr, ad_arr,
                                                  fold + 2 * l, bias + l * HID, hB,
                                                  (l < 3) ? 1 : 0);
    }

    // ---- pool + linear + relu ----
    k_pool<<<B_GR / 4, 256, 0, stream>>>(hB, lin_w, lin_b, out);
}